// Round 1
// baseline (427.617 us; speedup 1.0000x reference)
//
#include <hip/hip_runtime.h>
#include <hip/hip_bf16.h>

// Dims (fixed for this problem)
#define T_DIM 64
#define B_DIM 4
#define INP_D 768
#define Q_D   384
#define E_D   384
#define DFF_D 1536
#define NTOK  256   // T_DIM * B_DIM

__device__ __forceinline__ float sigf(float x)  { return 1.0f / (1.0f + __expf(-x)); }
__device__ __forceinline__ float elu1f(float x) { return x > 0.0f ? x + 1.0f : __expf(x); }

// ---------------------------------------------------------------------------
// Generic 64x64 f32 GEMM core: C-tile acc[4][4] per thread, 256 threads/block.
// A: M x K row-major, B: K x N row-major. No bounds checks (all dims % 64 == 0,
// K % 16 == 0 for every call site).
// ---------------------------------------------------------------------------
template<int K, int N>
__device__ __forceinline__ void gemm_core(const float* __restrict__ A,
                                          const float* __restrict__ Bm,
                                          float (*As)[68], float (*Bs)[68],
                                          float acc[4][4], int m0, int n0) {
  const int tid = threadIdx.x;
  const int tx = tid & 15, ty = tid >> 4;
  const int ar = tid >> 2, ac4 = (tid & 3) << 2;   // A-tile load: 64 rows x 16 k
  const int br = tid >> 4, bc4 = (tid & 15) << 2;  // B-tile load: 16 k x 64 cols
  for (int kb = 0; kb < K; kb += 16) {
    float4 av = *(const float4*)&A[(size_t)(m0 + ar) * K + kb + ac4];
    As[ac4 + 0][ar] = av.x;
    As[ac4 + 1][ar] = av.y;
    As[ac4 + 2][ar] = av.z;
    As[ac4 + 3][ar] = av.w;
    *(float4*)&Bs[br][bc4] = *(const float4*)&Bm[(size_t)(kb + br) * N + n0 + bc4];
    __syncthreads();
#pragma unroll
    for (int kk = 0; kk < 16; ++kk) {
      const float4 a4 = *(const float4*)&As[kk][ty << 2];
      const float4 b4 = *(const float4*)&Bs[kk][tx << 2];
      const float a[4] = {a4.x, a4.y, a4.z, a4.w};
      const float b[4] = {b4.x, b4.y, b4.z, b4.w};
#pragma unroll
      for (int i = 0; i < 4; ++i)
#pragma unroll
        for (int j = 0; j < 4; ++j) acc[i][j] = fmaf(a[i], b[j], acc[i][j]);
    }
    __syncthreads();
  }
}

// ---------------------------------------------------------------------------
// 1) mixed = mu * inp + (1-mu) * lasts  (lasts = prev-step inp, reset to
//    init_inp where is_first, forced init at t==0)
// ---------------------------------------------------------------------------
__global__ __launch_bounds__(256) void k_mixed(const float* __restrict__ inp,
                                               const float* __restrict__ is_first,
                                               const float* __restrict__ init_inp,
                                               const float* __restrict__ mu,
                                               float* __restrict__ mixed) {
  int idx = blockIdx.x * 256 + threadIdx.x;        // < NTOK*INP_D
  int c   = idx % INP_D;
  int tok = idx / INP_D;                           // t*B + b
  int t = tok >> 2, b = tok & 3;
  float last = (t == 0) ? 0.0f : inp[idx - B_DIM * INP_D];
  float m    = (t == 0) ? 1.0f : is_first[tok];
  float ii   = init_inp[b * INP_D + c];
  last += m * (ii - last);
  float muv = mu[c];
  mixed[idx] = muv * inp[idx] + (1.0f - muv) * last;
}

// ---------------------------------------------------------------------------
// 2) forget = (sigmoid(mixed @ mix_W) - 1) * drops + 1
// ---------------------------------------------------------------------------
__global__ __launch_bounds__(256) void k_gemm_forget(const float* __restrict__ mixed,
                                                     const float* __restrict__ mixW,
                                                     const float* __restrict__ drops,
                                                     float* __restrict__ forget) {
  __shared__ float As[16][68], Bs[16][68];
  float acc[4][4] = {};
  const int m0 = blockIdx.x * 64, n0 = blockIdx.y * 64;
  gemm_core<INP_D, Q_D>(mixed, mixW, As, Bs, acc, m0, n0);
  const int tx = threadIdx.x & 15, ty = threadIdx.x >> 4;
#pragma unroll
  for (int i = 0; i < 4; ++i) {
    int m = m0 + (ty << 2) + i;
    float d = drops[m];
#pragma unroll
    for (int j = 0; j < 4; ++j) {
      int n = n0 + (tx << 2) + j;
      float f = sigf(acc[i][j]);
      forget[(size_t)m * Q_D + n] = (f - 1.0f) * d + 1.0f;
    }
  }
}

// ---------------------------------------------------------------------------
// 3) parts = (inp @ layer_W) * drops   (raw, pre-activation)
// ---------------------------------------------------------------------------
__global__ __launch_bounds__(256) void k_gemm_parts(const float* __restrict__ inp,
                                                    const float* __restrict__ layerW,
                                                    const float* __restrict__ drops,
                                                    float* __restrict__ parts) {
  __shared__ float As[16][68], Bs[16][68];
  float acc[4][4] = {};
  const int m0 = blockIdx.x * 64, n0 = blockIdx.y * 64;
  gemm_core<INP_D, DFF_D>(inp, layerW, As, Bs, acc, m0, n0);
  const int tx = threadIdx.x & 15, ty = threadIdx.x >> 4;
#pragma unroll
  for (int i = 0; i < 4; ++i) {
    int m = m0 + (ty << 2) + i;
    float d = drops[m];
#pragma unroll
    for (int j = 0; j < 4; ++j) {
      int n = n0 + (tx << 2) + j;
      parts[(size_t)m * DFF_D + n] = acc[i][j] * d;
    }
  }
}

// ---------------------------------------------------------------------------
// 4) query = elu(parts[:, :Q])+1 ; keyv = elu(parts[:, Q:2Q])+1 ;
//    value = sigmoid(parts[:, 2Q:2Q+E]) * parts[:, 2Q+E:]
// ---------------------------------------------------------------------------
__global__ __launch_bounds__(256) void k_qkv(const float* __restrict__ parts,
                                             float* __restrict__ query,
                                             float* __restrict__ keyv,
                                             float* __restrict__ value) {
  int idx = blockIdx.x * 256 + threadIdx.x;        // < NTOK*Q_D
  int tok = idx / Q_D, c = idx % Q_D;
  const float* p = parts + (size_t)tok * DFF_D;
  query[idx] = elu1f(p[c]);
  keyv[idx]  = elu1f(p[Q_D + c]);
  value[idx] = sigf(p[2 * Q_D + c]) * p[2 * Q_D + E_D + c];
}

// ---------------------------------------------------------------------------
// 5) Segmented linear scan + query contraction.
//    states[t] = f[t] * prev + keyv[t] (x) value[t];  prev = init on restart.
//    att[t,b,e] += sum_q query[t,b,q] * states[t,b,q,e]   (atomic partial sums)
//    Grid: (E/64 e-tiles, Q/96 q-chunks, B). Block 256 = 64 e-lanes x 4 q-subgroups.
//    Each thread holds 24 state elements (q-stripe) in registers.
// ---------------------------------------------------------------------------
__global__ __launch_bounds__(256) void k_scan(const float* __restrict__ forget,
                                              const float* __restrict__ query,
                                              const float* __restrict__ keyv,
                                              const float* __restrict__ value,
                                              const float* __restrict__ is_first,
                                              const float* __restrict__ init_state,
                                              float* __restrict__ att) {
  const int e  = blockIdx.x * 64 + (threadIdx.x & 63);
  const int qg = threadIdx.x >> 6;                 // 0..3
  const int q0 = blockIdx.y * 96 + qg * 24;
  const int b  = blockIdx.z;

  float s[24], ini[24];
#pragma unroll
  for (int j = 0; j < 24; ++j) {
    ini[j] = init_state[(size_t)b * (Q_D * E_D) + (size_t)(q0 + j) * E_D + e];
    s[j]   = ini[j];
  }

  for (int t = 0; t < T_DIM; ++t) {
    const int tok = t * B_DIM + b;
    if (t > 0 && is_first[tok] > 0.5f) {
#pragma unroll
      for (int j = 0; j < 24; ++j) s[j] = ini[j];
    }
    const float v = value[(size_t)tok * E_D + e];
    const float* fq = forget + (size_t)tok * Q_D + q0;
    const float* kq = keyv   + (size_t)tok * Q_D + q0;
    const float* qq = query  + (size_t)tok * Q_D + q0;
    float p = 0.0f;
#pragma unroll
    for (int j = 0; j < 24; ++j) {
      s[j] = fmaf(fq[j], s[j], kq[j] * v);
      p    = fmaf(qq[j], s[j], p);
    }
    atomicAdd(&att[(size_t)tok * E_D + e], p);
  }
}

// ---------------------------------------------------------------------------
// 6) RMS norm over E, scale by rms_w
// ---------------------------------------------------------------------------
__global__ __launch_bounds__(128) void k_rms(const float* __restrict__ att,
                                             const float* __restrict__ rms_w,
                                             float* __restrict__ attn) {
  const int tok = blockIdx.x, tid = threadIdx.x;
  float x[3], ss = 0.0f;
#pragma unroll
  for (int i = 0; i < 3; ++i) {
    x[i] = att[(size_t)tok * E_D + i * 128 + tid];
    ss = fmaf(x[i], x[i], ss);
  }
#pragma unroll
  for (int off = 32; off; off >>= 1) ss += __shfl_down(ss, off, 64);
  __shared__ float r[2];
  const int wid = tid >> 6, lane = tid & 63;
  if (lane == 0) r[wid] = ss;
  __syncthreads();
  ss = r[0] + r[1];
  const float sc = rsqrtf(ss * (1.0f / E_D) + 1e-6f);
#pragma unroll
  for (int i = 0; i < 3; ++i) {
    int c = i * 128 + tid;
    attn[(size_t)tok * E_D + c] = x[i] * sc * rms_w[c];
  }
}

// ---------------------------------------------------------------------------
// 7) hpre = attn @ proj_W + inp   (residual in epilogue)
// ---------------------------------------------------------------------------
__global__ __launch_bounds__(256) void k_gemm_proj(const float* __restrict__ attn,
                                                   const float* __restrict__ projW,
                                                   const float* __restrict__ inp,
                                                   float* __restrict__ hpre) {
  __shared__ float As[16][68], Bs[16][68];
  float acc[4][4] = {};
  const int m0 = blockIdx.x * 64, n0 = blockIdx.y * 64;
  gemm_core<E_D, INP_D>(attn, projW, As, Bs, acc, m0, n0);
  const int tx = threadIdx.x & 15, ty = threadIdx.x >> 4;
#pragma unroll
  for (int i = 0; i < 4; ++i) {
    int m = m0 + (ty << 2) + i;
#pragma unroll
    for (int j = 0; j < 4; ++j) {
      int n = n0 + (tx << 2) + j;
      hpre[(size_t)m * INP_D + n] = acc[i][j] + inp[(size_t)m * INP_D + n];
    }
  }
}

// ---------------------------------------------------------------------------
// 8) LayerNorm over INP (768 = 3*256)
// ---------------------------------------------------------------------------
__global__ __launch_bounds__(256) void k_ln(const float* __restrict__ hpre,
                                            const float* __restrict__ ln_w,
                                            const float* __restrict__ ln_b,
                                            float* __restrict__ h) {
  const int tok = blockIdx.x, tid = threadIdx.x;
  float x[3], s1 = 0.0f, s2 = 0.0f;
#pragma unroll
  for (int i = 0; i < 3; ++i) {
    x[i] = hpre[(size_t)tok * INP_D + i * 256 + tid];
    s1 += x[i];
    s2 = fmaf(x[i], x[i], s2);
  }
#pragma unroll
  for (int off = 32; off; off >>= 1) {
    s1 += __shfl_down(s1, off, 64);
    s2 += __shfl_down(s2, off, 64);
  }
  __shared__ float r1[4], r2[4];
  const int wid = tid >> 6, lane = tid & 63;
  if (lane == 0) { r1[wid] = s1; r2[wid] = s2; }
  __syncthreads();
  s1 = r1[0] + r1[1] + r1[2] + r1[3];
  s2 = r2[0] + r2[1] + r2[2] + r2[3];
  const float mean = s1 * (1.0f / INP_D);
  const float var  = s2 * (1.0f / INP_D) - mean * mean;
  const float sc   = rsqrtf(var + 1e-5f);
#pragma unroll
  for (int i = 0; i < 3; ++i) {
    int c = i * 256 + tid;
    h[(size_t)tok * INP_D + c] = (x[i] - mean) * sc * ln_w[c] + ln_b[c];
  }
}

// ---------------------------------------------------------------------------
// 9) g = silu(h @ W1) * (h @ W2)  — dual-B GEMM sharing the A tile
// ---------------------------------------------------------------------------
__global__ __launch_bounds__(256) void k_gemm_ffn12(const float* __restrict__ h,
                                                    const float* __restrict__ W1,
                                                    const float* __restrict__ W2,
                                                    float* __restrict__ g) {
  __shared__ float As[16][68], B1s[16][68], B2s[16][68];
  float acc1[4][4] = {}, acc2[4][4] = {};
  const int tid = threadIdx.x;
  const int tx = tid & 15, ty = tid >> 4;
  const int ar = tid >> 2, ac4 = (tid & 3) << 2;
  const int br = tid >> 4, bc4 = (tid & 15) << 2;
  const int m0 = blockIdx.x * 64, n0 = blockIdx.y * 64;
  for (int kb = 0; kb < INP_D; kb += 16) {
    float4 av = *(const float4*)&h[(size_t)(m0 + ar) * INP_D + kb + ac4];
    As[ac4 + 0][ar] = av.x;
    As[ac4 + 1][ar] = av.y;
    As[ac4 + 2][ar] = av.z;
    As[ac4 + 3][ar] = av.w;
    *(float4*)&B1s[br][bc4] = *(const float4*)&W1[(size_t)(kb + br) * DFF_D + n0 + bc4];
    *(float4*)&B2s[br][bc4] = *(const float4*)&W2[(size_t)(kb + br) * DFF_D + n0 + bc4];
    __syncthreads();
#pragma unroll
    for (int kk = 0; kk < 16; ++kk) {
      const float4 a4 = *(const float4*)&As[kk][ty << 2];
      const float4 b14 = *(const float4*)&B1s[kk][tx << 2];
      const float4 b24 = *(const float4*)&B2s[kk][tx << 2];
      const float a[4]  = {a4.x, a4.y, a4.z, a4.w};
      const float b1[4] = {b14.x, b14.y, b14.z, b14.w};
      const float b2[4] = {b24.x, b24.y, b24.z, b24.w};
#pragma unroll
      for (int i = 0; i < 4; ++i)
#pragma unroll
        for (int j = 0; j < 4; ++j) {
          acc1[i][j] = fmaf(a[i], b1[j], acc1[i][j]);
          acc2[i][j] = fmaf(a[i], b2[j], acc2[i][j]);
        }
    }
    __syncthreads();
  }
#pragma unroll
  for (int i = 0; i < 4; ++i) {
    int m = m0 + (ty << 2) + i;
#pragma unroll
    for (int j = 0; j < 4; ++j) {
      int n = n0 + (tx << 2) + j;
      float a = acc1[i][j], bb = acc2[i][j];
      g[(size_t)m * DFF_D + n] = a * sigf(a) * bb;
    }
  }
}

// ---------------------------------------------------------------------------
// 10) out = g @ W3
// ---------------------------------------------------------------------------
__global__ __launch_bounds__(256) void k_gemm_out(const float* __restrict__ g,
                                                  const float* __restrict__ W3,
                                                  float* __restrict__ out) {
  __shared__ float As[16][68], Bs[16][68];
  float acc[4][4] = {};
  const int m0 = blockIdx.x * 64, n0 = blockIdx.y * 64;
  gemm_core<DFF_D, INP_D>(g, W3, As, Bs, acc, m0, n0);
  const int tx = threadIdx.x & 15, ty = threadIdx.x >> 4;
#pragma unroll
  for (int i = 0; i < 4; ++i) {
    int m = m0 + (ty << 2) + i;
#pragma unroll
    for (int j = 0; j < 4; ++j) {
      int n = n0 + (tx << 2) + j;
      out[(size_t)m * INP_D + n] = acc[i][j];
    }
  }
}

// ---------------------------------------------------------------------------
// Workspace layout (float offsets)
// ---------------------------------------------------------------------------
#define WS_MIXED  0
#define WS_PARTS  (WS_MIXED + NTOK * INP_D)       // 196608
#define WS_FORGET (WS_PARTS + NTOK * DFF_D)       // +393216
#define WS_QUERY  (WS_FORGET + NTOK * Q_D)
#define WS_KEYV   (WS_QUERY + NTOK * Q_D)
#define WS_VALUE  (WS_KEYV + NTOK * Q_D)
#define WS_ATT    (WS_VALUE + NTOK * E_D)
#define WS_ATTN   (WS_ATT + NTOK * E_D)
#define WS_HPRE   (WS_ATTN + NTOK * E_D)
#define WS_H      (WS_HPRE + NTOK * INP_D)
#define WS_G      (WS_H + NTOK * INP_D)

extern "C" void kernel_launch(void* const* d_in, const int* in_sizes, int n_in,
                              void* d_out, int out_size, void* d_ws, size_t ws_size,
                              hipStream_t stream) {
  (void)in_sizes; (void)n_in; (void)out_size; (void)ws_size;
  const float* inp        = (const float*)d_in[0];
  const float* is_first   = (const float*)d_in[1];
  const float* drops      = (const float*)d_in[2];
  const float* init_inp   = (const float*)d_in[3];
  const float* init_state = (const float*)d_in[4];
  const float* mix_mu     = (const float*)d_in[5];
  const float* mix_W      = (const float*)d_in[6];
  const float* layer_W    = (const float*)d_in[7];
  const float* proj_W     = (const float*)d_in[8];
  const float* rms_w      = (const float*)d_in[9];
  const float* ln_w       = (const float*)d_in[10];
  const float* ln_b       = (const float*)d_in[11];
  const float* W1         = (const float*)d_in[12];
  const float* W2         = (const float*)d_in[13];
  const float* W3         = (const float*)d_in[14];
  float* out = (float*)d_out;
  float* ws  = (float*)d_ws;

  float* mixed  = ws + WS_MIXED;
  float* parts  = ws + WS_PARTS;
  float* forget = ws + WS_FORGET;
  float* query  = ws + WS_QUERY;
  float* keyv   = ws + WS_KEYV;
  float* value  = ws + WS_VALUE;
  float* att    = ws + WS_ATT;
  float* attn   = ws + WS_ATTN;
  float* hpre   = ws + WS_HPRE;
  float* h      = ws + WS_H;
  float* g      = ws + WS_G;

  // att accumulates via atomics — zero it first
  hipMemsetAsync(att, 0, (size_t)NTOK * E_D * sizeof(float), stream);

  k_mixed<<<NTOK * INP_D / 256, 256, 0, stream>>>(inp, is_first, init_inp, mix_mu, mixed);
  k_gemm_forget<<<dim3(NTOK / 64, Q_D / 64), 256, 0, stream>>>(mixed, mix_W, drops, forget);
  k_gemm_parts<<<dim3(NTOK / 64, DFF_D / 64), 256, 0, stream>>>(inp, layer_W, drops, parts);
  k_qkv<<<NTOK * Q_D / 256, 256, 0, stream>>>(parts, query, keyv, value);
  k_scan<<<dim3(E_D / 64, Q_D / 96, B_DIM), 256, 0, stream>>>(forget, query, keyv, value,
                                                              is_first, init_state, att);
  k_rms<<<NTOK, 128, 0, stream>>>(att, rms_w, attn);
  k_gemm_proj<<<dim3(NTOK / 64, INP_D / 64), 256, 0, stream>>>(attn, proj_W, inp, hpre);
  k_ln<<<NTOK, 256, 0, stream>>>(hpre, ln_w, ln_b, h);
  k_gemm_ffn12<<<dim3(NTOK / 64, DFF_D / 64), 256, 0, stream>>>(h, W1, W2, g);
  k_gemm_out<<<dim3(NTOK / 64, INP_D / 64), 256, 0, stream>>>(g, W3, out);
}

// Round 2
// 227.638 us; speedup vs baseline: 1.8785x; 1.8785x over previous
//
#include <hip/hip_runtime.h>
#include <hip/hip_bf16.h>

#define T_DIM 64
#define B_DIM 4
#define INP_D 768
#define Q_D   384
#define E_D   384
#define DFF_D 1536
#define NTOK  256   // T_DIM * B_DIM

__device__ __forceinline__ float sigf(float x)  { return 1.0f / (1.0f + __expf(-x)); }
__device__ __forceinline__ float elu1f(float x) { return x > 0.0f ? x + 1.0f : __expf(x); }

// ---------------------------------------------------------------------------
// Split-K GEMM: A[256 x K] row-major, B[K x N] row-major.
// Tile 64x64, 512 threads (8 waves). Grid (4, N/64, S). Each split-z writes its
// own partial slab P[s][256][N] (no atomics). Threads<256 stage A, >=256 stage B.
// Per-thread C: 2 rows x 4 cols.
// ---------------------------------------------------------------------------
template<int K, int N, int S>
__global__ __launch_bounds__(512) void gemm_sk(const float* __restrict__ A,
                                               const float* __restrict__ Bm,
                                               float* __restrict__ P) {
  constexpr int Ksub = K / S;
  __shared__ float As[16][66], Bs[16][68];
  const int tid = threadIdx.x;
  const int m0 = blockIdx.x * 64, n0 = blockIdx.y * 64, sz = blockIdx.z;
  const int k0 = sz * Ksub;
  const int tx = tid & 15, ty = tid >> 4;            // ty 0..31
  const int ar = (tid & 255) >> 2, ac = (tid & 3) << 2;
  const int br = (tid & 255) >> 4, bc = (tid & 15) << 2;
  float acc[2][4] = {};
  float4 ra, rb;
  if (tid < 256) ra = *(const float4*)&A[(size_t)(m0 + ar) * K + k0 + ac];
  else           rb = *(const float4*)&Bm[(size_t)(k0 + br) * N + n0 + bc];
  for (int kb = 0; kb < Ksub; kb += 16) {
    if (kb) __syncthreads();
    if (tid < 256) { As[ac+0][ar]=ra.x; As[ac+1][ar]=ra.y; As[ac+2][ar]=ra.z; As[ac+3][ar]=ra.w; }
    else           { *(float4*)&Bs[br][bc] = rb; }
    __syncthreads();
    if (kb + 16 < Ksub) {
      if (tid < 256) ra = *(const float4*)&A[(size_t)(m0 + ar) * K + k0 + kb + 16 + ac];
      else           rb = *(const float4*)&Bm[(size_t)(k0 + kb + 16 + br) * N + n0 + bc];
    }
#pragma unroll
    for (int kk = 0; kk < 16; ++kk) {
      const float2 a  = *(const float2*)&As[kk][ty << 1];
      const float4 b4 = *(const float4*)&Bs[kk][tx << 2];
      acc[0][0] = fmaf(a.x, b4.x, acc[0][0]);
      acc[0][1] = fmaf(a.x, b4.y, acc[0][1]);
      acc[0][2] = fmaf(a.x, b4.z, acc[0][2]);
      acc[0][3] = fmaf(a.x, b4.w, acc[0][3]);
      acc[1][0] = fmaf(a.y, b4.x, acc[1][0]);
      acc[1][1] = fmaf(a.y, b4.y, acc[1][1]);
      acc[1][2] = fmaf(a.y, b4.z, acc[1][2]);
      acc[1][3] = fmaf(a.y, b4.w, acc[1][3]);
    }
  }
#pragma unroll
  for (int i = 0; i < 2; ++i) {
    float4 v = make_float4(acc[i][0], acc[i][1], acc[i][2], acc[i][3]);
    *(float4*)&P[((size_t)sz * NTOK + m0 + (ty << 1) + i) * N + n0 + (tx << 2)] = v;
  }
}

// ---------------------------------------------------------------------------
// Forget GEMM with "mixed" fused into A staging.
// A_synth[m][k] = mu[k]*inp[m][k] + (1-mu[k])*last, last = init_inp or inp[m-4].
// ---------------------------------------------------------------------------
template<int S>
__global__ __launch_bounds__(512) void gemm_forget_sk(const float* __restrict__ inp,
                                                      const float* __restrict__ is_first,
                                                      const float* __restrict__ init_inp,
                                                      const float* __restrict__ mu,
                                                      const float* __restrict__ Bm,
                                                      float* __restrict__ P) {
  constexpr int K = INP_D, N = Q_D;
  constexpr int Ksub = K / S;
  __shared__ float As[16][66], Bs[16][68];
  const int tid = threadIdx.x;
  const int m0 = blockIdx.x * 64, n0 = blockIdx.y * 64, sz = blockIdx.z;
  const int k0 = sz * Ksub;
  const int tx = tid & 15, ty = tid >> 4;
  const int ar = (tid & 255) >> 2, ac = (tid & 3) << 2;
  const int br = (tid & 255) >> 4, bc = (tid & 15) << 2;
  const int m = m0 + ar, t = m >> 2, b = m & 3;
  const float fr = (t == 0) ? 1.0f : is_first[m];
  float acc[2][4] = {};
  float4 ra, rb;
  auto synthA = [&](int kc) {
    float4 xi = *(const float4*)&inp[(size_t)m * K + kc];
    float4 la = (fr > 0.5f) ? *(const float4*)&init_inp[b * K + kc]
                            : *(const float4*)&inp[(size_t)(m - 4) * K + kc];
    float4 m4 = *(const float4*)&mu[kc];
    float4 r;
    r.x = m4.x * xi.x + (1.0f - m4.x) * la.x;
    r.y = m4.y * xi.y + (1.0f - m4.y) * la.y;
    r.z = m4.z * xi.z + (1.0f - m4.z) * la.z;
    r.w = m4.w * xi.w + (1.0f - m4.w) * la.w;
    return r;
  };
  if (tid < 256) ra = synthA(k0 + ac);
  else           rb = *(const float4*)&Bm[(size_t)(k0 + br) * N + n0 + bc];
  for (int kb = 0; kb < Ksub; kb += 16) {
    if (kb) __syncthreads();
    if (tid < 256) { As[ac+0][ar]=ra.x; As[ac+1][ar]=ra.y; As[ac+2][ar]=ra.z; As[ac+3][ar]=ra.w; }
    else           { *(float4*)&Bs[br][bc] = rb; }
    __syncthreads();
    if (kb + 16 < Ksub) {
      if (tid < 256) ra = synthA(k0 + kb + 16 + ac);
      else           rb = *(const float4*)&Bm[(size_t)(k0 + kb + 16 + br) * N + n0 + bc];
    }
#pragma unroll
    for (int kk = 0; kk < 16; ++kk) {
      const float2 a  = *(const float2*)&As[kk][ty << 1];
      const float4 b4 = *(const float4*)&Bs[kk][tx << 2];
      acc[0][0] = fmaf(a.x, b4.x, acc[0][0]);
      acc[0][1] = fmaf(a.x, b4.y, acc[0][1]);
      acc[0][2] = fmaf(a.x, b4.z, acc[0][2]);
      acc[0][3] = fmaf(a.x, b4.w, acc[0][3]);
      acc[1][0] = fmaf(a.y, b4.x, acc[1][0]);
      acc[1][1] = fmaf(a.y, b4.y, acc[1][1]);
      acc[1][2] = fmaf(a.y, b4.z, acc[1][2]);
      acc[1][3] = fmaf(a.y, b4.w, acc[1][3]);
    }
  }
#pragma unroll
  for (int i = 0; i < 2; ++i) {
    float4 v = make_float4(acc[i][0], acc[i][1], acc[i][2], acc[i][3]);
    *(float4*)&P[((size_t)sz * NTOK + m0 + (ty << 1) + i) * N + n0 + (tx << 2)] = v;
  }
}

// ---------------------------------------------------------------------------
// Dual-B FFN GEMM (shares A tile): writes raw partials for W1 and W2 paths.
// ---------------------------------------------------------------------------
template<int S>
__global__ __launch_bounds__(512) void gemm_ffn_sk(const float* __restrict__ A,
                                                   const float* __restrict__ B1,
                                                   const float* __restrict__ B2,
                                                   float* __restrict__ P1,
                                                   float* __restrict__ P2) {
  constexpr int K = INP_D, N = DFF_D;
  constexpr int Ksub = K / S;
  __shared__ float As[16][66], B1s[16][68], B2s[16][68];
  const int tid = threadIdx.x;
  const int m0 = blockIdx.x * 64, n0 = blockIdx.y * 64, sz = blockIdx.z;
  const int k0 = sz * Ksub;
  const int tx = tid & 15, ty = tid >> 4;
  const int ar = (tid & 255) >> 2, ac = (tid & 3) << 2;
  const int br = (tid & 255) >> 4, bc = (tid & 15) << 2;
  const int b2r = (tid >> 4) & 15, b2c = (tid & 15) << 2;
  float acc1[2][4] = {}, acc2[2][4] = {};
  float4 ra, rb, rb2;
  if (tid < 256) {
    ra  = *(const float4*)&A[(size_t)(m0 + ar) * K + k0 + ac];
    rb2 = *(const float4*)&B2[(size_t)(k0 + b2r) * N + n0 + b2c];
  } else {
    rb  = *(const float4*)&B1[(size_t)(k0 + br) * N + n0 + bc];
  }
  for (int kb = 0; kb < Ksub; kb += 16) {
    if (kb) __syncthreads();
    if (tid < 256) {
      As[ac+0][ar]=ra.x; As[ac+1][ar]=ra.y; As[ac+2][ar]=ra.z; As[ac+3][ar]=ra.w;
      *(float4*)&B2s[b2r][b2c] = rb2;
    } else {
      *(float4*)&B1s[br][bc] = rb;
    }
    __syncthreads();
    if (kb + 16 < Ksub) {
      if (tid < 256) {
        ra  = *(const float4*)&A[(size_t)(m0 + ar) * K + k0 + kb + 16 + ac];
        rb2 = *(const float4*)&B2[(size_t)(k0 + kb + 16 + b2r) * N + n0 + b2c];
      } else {
        rb  = *(const float4*)&B1[(size_t)(k0 + kb + 16 + br) * N + n0 + bc];
      }
    }
#pragma unroll
    for (int kk = 0; kk < 16; ++kk) {
      const float2 a  = *(const float2*)&As[kk][ty << 1];
      const float4 c1 = *(const float4*)&B1s[kk][tx << 2];
      const float4 c2 = *(const float4*)&B2s[kk][tx << 2];
#pragma unroll
      for (int j = 0; j < 4; ++j) {
        const float b1j = (&c1.x)[j], b2j = (&c2.x)[j];
        acc1[0][j] = fmaf(a.x, b1j, acc1[0][j]);
        acc1[1][j] = fmaf(a.y, b1j, acc1[1][j]);
        acc2[0][j] = fmaf(a.x, b2j, acc2[0][j]);
        acc2[1][j] = fmaf(a.y, b2j, acc2[1][j]);
      }
    }
  }
#pragma unroll
  for (int i = 0; i < 2; ++i) {
    size_t o = ((size_t)sz * NTOK + m0 + (ty << 1) + i) * N + n0 + (tx << 2);
    *(float4*)&P1[o] = make_float4(acc1[i][0], acc1[i][1], acc1[i][2], acc1[i][3]);
    *(float4*)&P2[o] = make_float4(acc2[i][0], acc2[i][1], acc2[i][2], acc2[i][3]);
  }
}

// ---------------------------------------------------------------------------
// Epilogues
// ---------------------------------------------------------------------------
__global__ __launch_bounds__(256) void ep_forget(const float* __restrict__ pf,
                                                 const float* __restrict__ drops,
                                                 float* __restrict__ forget) {
  int idx = blockIdx.x * 256 + threadIdx.x;          // < NTOK*Q_D
  float s = pf[idx] + pf[98304 + idx] + pf[196608 + idx] + pf[294912 + idx];
  float f = sigf(s);
  forget[idx] = (f - 1.0f) * drops[idx / Q_D] + 1.0f;
}

__global__ __launch_bounds__(256) void ep_qkv(const float* __restrict__ pp,
                                              const float* __restrict__ drops,
                                              float* __restrict__ query,
                                              float* __restrict__ keyv,
                                              float* __restrict__ value) {
  int idx = blockIdx.x * 256 + threadIdx.x;          // < NTOK*Q_D
  int m = idx / Q_D, c = idx % Q_D;
  float d = drops[m];
  size_t base = (size_t)m * DFF_D;
  auto P = [&](int col) { return (pp[base + col] + pp[393216 + base + col]) * d; };
  query[idx] = elu1f(P(c));
  keyv[idx]  = elu1f(P(Q_D + c));
  value[idx] = sigf(P(2 * Q_D + c)) * P(2 * Q_D + E_D + c);
}

// sum 8 scan partials + RMS norm
__global__ __launch_bounds__(128) void ep_rms(const float* __restrict__ patt,
                                              const float* __restrict__ rms_w,
                                              float* __restrict__ attn) {
  const int tok = blockIdx.x, tid = threadIdx.x;
  float x[3], ss = 0.0f;
#pragma unroll
  for (int i = 0; i < 3; ++i) {
    int e = i * 128 + tid;
    float a = 0.0f;
#pragma unroll
    for (int qc = 0; qc < 8; ++qc) a += patt[((size_t)qc * NTOK + tok) * E_D + e];
    x[i] = a;
    ss = fmaf(a, a, ss);
  }
#pragma unroll
  for (int off = 32; off; off >>= 1) ss += __shfl_down(ss, off, 64);
  __shared__ float r[2];
  const int wid = tid >> 6, lane = tid & 63;
  if (lane == 0) r[wid] = ss;
  __syncthreads();
  ss = r[0] + r[1];
  const float sc = rsqrtf(ss * (1.0f / E_D) + 1e-6f);
#pragma unroll
  for (int i = 0; i < 3; ++i) {
    int e = i * 128 + tid;
    attn[(size_t)tok * E_D + e] = x[i] * sc * rms_w[e];
  }
}

// sum 4 proj partials + residual + LayerNorm
__global__ __launch_bounds__(256) void ep_ln(const float* __restrict__ pproj,
                                             const float* __restrict__ inp,
                                             const float* __restrict__ ln_w,
                                             const float* __restrict__ ln_b,
                                             float* __restrict__ h) {
  const int tok = blockIdx.x, tid = threadIdx.x;
  float x[3], s1 = 0.0f, s2 = 0.0f;
#pragma unroll
  for (int i = 0; i < 3; ++i) {
    int c = i * 256 + tid;
    float a = inp[(size_t)tok * INP_D + c];
#pragma unroll
    for (int s = 0; s < 4; ++s) a += pproj[((size_t)s * NTOK + tok) * INP_D + c];
    x[i] = a;
    s1 += a;
    s2 = fmaf(a, a, s2);
  }
#pragma unroll
  for (int off = 32; off; off >>= 1) {
    s1 += __shfl_down(s1, off, 64);
    s2 += __shfl_down(s2, off, 64);
  }
  __shared__ float r1[4], r2[4];
  const int wid = tid >> 6, lane = tid & 63;
  if (lane == 0) { r1[wid] = s1; r2[wid] = s2; }
  __syncthreads();
  s1 = r1[0] + r1[1] + r1[2] + r1[3];
  s2 = r2[0] + r2[1] + r2[2] + r2[3];
  const float mean = s1 * (1.0f / INP_D);
  const float var  = s2 * (1.0f / INP_D) - mean * mean;
  const float sc   = rsqrtf(var + 1e-5f);
#pragma unroll
  for (int i = 0; i < 3; ++i) {
    int c = i * 256 + tid;
    h[(size_t)tok * INP_D + c] = (x[i] - mean) * sc * ln_w[c] + ln_b[c];
  }
}

__global__ __launch_bounds__(256) void ep_ffng(const float* __restrict__ p1,
                                               const float* __restrict__ p2,
                                               float* __restrict__ g) {
  int idx = blockIdx.x * 256 + threadIdx.x;          // < NTOK*DFF_D
  float a = p1[idx] + p1[393216 + idx];
  float b = p2[idx] + p2[393216 + idx];
  g[idx] = a * sigf(a) * b;
}

__global__ __launch_bounds__(256) void ep_out(const float* __restrict__ po,
                                              float* __restrict__ out) {
  int idx = blockIdx.x * 256 + threadIdx.x;          // < NTOK*INP_D
  out[idx] = po[idx] + po[196608 + idx] + po[393216 + idx] + po[589824 + idx];
}

// ---------------------------------------------------------------------------
// Segmented scan, LDS-staged with register prefetch.
// Grid (E/64=6, QC=8, B=4) = 192 blocks, 256 threads (4 waves).
// q-chunk = 48 per block, 12 states per thread. Writes patt[qc][tok][e].
// ---------------------------------------------------------------------------
__global__ __launch_bounds__(256) void k_scan(const float* __restrict__ forget,
                                              const float* __restrict__ query,
                                              const float* __restrict__ keyv,
                                              const float* __restrict__ value,
                                              const float* __restrict__ is_first,
                                              const float* __restrict__ init_state,
                                              float* __restrict__ patt) {
  __shared__ float stg[144];     // f[48] k[48] q[48]
  __shared__ float pacc[256];
  const int tid = threadIdx.x;
  const int e  = blockIdx.x * 64 + (tid & 63);
  const int qg = tid >> 6;                       // 0..3
  const int qc = blockIdx.y;
  const int b  = blockIdx.z;
  const int q0 = qc * 48 + qg * 12;

  float s[12], ini[12];
#pragma unroll
  for (int j = 0; j < 12; ++j) {
    ini[j] = init_state[((size_t)b * Q_D + q0 + j) * E_D + e];
    s[j]   = ini[j];
  }

  // prefetch t=0
  float stage_r = 0.0f, v_r, if_r;
  {
    const int tok = b;
    if (tid < 144) {
      int which = tid / 48, o = tid % 48;
      const float* src = which == 0 ? forget : (which == 1 ? keyv : query);
      stage_r = src[(size_t)tok * Q_D + qc * 48 + o];
    }
    v_r  = value[(size_t)tok * E_D + e];
    if_r = 0.0f;  // t==0 handled by init already in s
  }

  for (int t = 0; t < T_DIM; ++t) {
    const int tok = t * B_DIM + b;
    if (tid < 144) stg[tid] = stage_r;
    const float v  = v_r;
    const float ff = if_r;
    __syncthreads();
    // prefetch t+1 (latency hides under compute below)
    if (t + 1 < T_DIM) {
      const int tok1 = tok + B_DIM;
      if (tid < 144) {
        int which = tid / 48, o = tid % 48;
        const float* src = which == 0 ? forget : (which == 1 ? keyv : query);
        stage_r = src[(size_t)tok1 * Q_D + qc * 48 + o];
      }
      v_r  = value[(size_t)tok1 * E_D + e];
      if_r = is_first[tok1];
    }
    if (ff > 0.5f) {
#pragma unroll
      for (int j = 0; j < 12; ++j) s[j] = ini[j];
    }
    const float4* f4 = (const float4*)&stg[qg * 12];
    const float4* k4 = (const float4*)&stg[48 + qg * 12];
    const float4* q4 = (const float4*)&stg[96 + qg * 12];
    float p = 0.0f;
#pragma unroll
    for (int jj = 0; jj < 3; ++jj) {
      const float4 fv = f4[jj], kv = k4[jj], qv = q4[jj];
#pragma unroll
      for (int j = 0; j < 4; ++j) {
        const int sj = jj * 4 + j;
        s[sj] = fmaf((&fv.x)[j], s[sj], (&kv.x)[j] * v);
        p     = fmaf((&qv.x)[j], s[sj], p);
      }
    }
    pacc[tid] = p;
    __syncthreads();
    if (tid < 64) {
      float r = pacc[tid] + pacc[tid + 64] + pacc[tid + 128] + pacc[tid + 192];
      patt[((size_t)qc * NTOK + tok) * E_D + blockIdx.x * 64 + tid] = r;
    }
  }
}

// ---------------------------------------------------------------------------
// Workspace layout (float offsets) — peak 1,966,080 floats = 7.86 MB
// slot0 @0       [786432]: pf_parts / patt / {h @393216, pf_f1 @0}
// slot1 @786432  [786432]: pf_fg / pf_proj / pf_f2 / pf_out
// slot2 @1572864 [393216]: forget@+0, q@+98304, k@+196608, v@+294912 / attn@+0 / g@+0
// ---------------------------------------------------------------------------
#define SLOT0 0
#define SLOT1 786432
#define SLOT2 1572864

extern "C" void kernel_launch(void* const* d_in, const int* in_sizes, int n_in,
                              void* d_out, int out_size, void* d_ws, size_t ws_size,
                              hipStream_t stream) {
  (void)in_sizes; (void)n_in; (void)out_size; (void)ws_size;
  const float* inp        = (const float*)d_in[0];
  const float* is_first   = (const float*)d_in[1];
  const float* drops      = (const float*)d_in[2];
  const float* init_inp   = (const float*)d_in[3];
  const float* init_state = (const float*)d_in[4];
  const float* mix_mu     = (const float*)d_in[5];
  const float* mix_W      = (const float*)d_in[6];
  const float* layer_W    = (const float*)d_in[7];
  const float* proj_W     = (const float*)d_in[8];
  const float* rms_w      = (const float*)d_in[9];
  const float* ln_w       = (const float*)d_in[10];
  const float* ln_b       = (const float*)d_in[11];
  const float* W1         = (const float*)d_in[12];
  const float* W2         = (const float*)d_in[13];
  const float* W3         = (const float*)d_in[14];
  float* out = (float*)d_out;
  float* ws  = (float*)d_ws;

  float* pf_parts = ws + SLOT0;            // [2][256][1536]
  float* patt     = ws + SLOT0;            // [8][256][384]
  float* h        = ws + SLOT0 + 393216;   // [256][768]
  float* pf_f1    = ws + SLOT0;            // [2][256][1536]... wait: pf_f1 needs 786432
  // NOTE: pf_f1 must coexist with h (g_ffn12 reads h, writes pf_f1/pf_f2).
  // pf_f1 @ SLOT0[0..393216) holds split 0 only; split 1 goes to SLOT2 later?
  // -> Simpler: ffn uses S=1? No. Re-derive: put pf_f1 split slabs at
  //    SLOT0[0..393216) and SLOT1[0..393216)+pf_f2 at SLOT1[393216..786432)
  //    is wrong (pf_f2 needs 786432). Resolve: ffn partial slabs:
  //    pf_f1: s0 @ SLOT0+0, s1 @ SLOT0+... h occupies [393216,589824).
  //    Use SLOT0 [0,393216) for pf_f1 s0 and SLOT0 [589824,786432)=196608 too small.
  // Final resolution (kept simple): ffn GEMM uses S=2 but writes slab s into
  // P + s*393216 where P blocks are pf_f1a/pf_f1b chosen disjoint from h:
  float* pf_f1a   = ws + SLOT0;            // [256][1536] split 0  [0,393216)
  float* pf_f2a   = ws + SLOT1;            // split 0 of W2 path   [786432,1179648)
  float* pf_f1b   = ws + SLOT1 + 393216;   // split 1 of W1 path   [1179648,1572864)
  float* pf_f2b   = ws + SLOT0 + 589824;   // 196608 floats... INSUFFICIENT (needs 393216)
  (void)pf_f1; (void)pf_f1a; (void)pf_f2a; (void)pf_f1b; (void)pf_f2b;

  // --- Clean final layout (verified below, 7.86 MB total) ---
  // stage:                buffers live
  //  fg GEMM/ep:          pf_fg @SLOT1 [393216], forget @SLOT2 [98304]
  //  parts GEMM/ep:       pf_parts @SLOT0 [786432], q/k/v @SLOT2+98304..
  //  scan/ep_rms:         patt @SLOT0 [786432], attn @SLOT2
  //  proj/ep_ln:          pf_proj @SLOT1 [786432], h @SLOT2+98304 [196608]
  //  ffn GEMM/ep:         pf_f1 @SLOT0 [786432], pf_f2 @SLOT1 [786432], g @SLOT2? [393216]
  //     (h @SLOT2+98304 read while pf_f1/pf_f2 written -> disjoint OK;
  //      g written by ep_ffng after pf read -> g @SLOT2+0 would overlap h? h dead after ffn GEMM.
  //      ep_ffng reads pf_f1/pf_f2 only -> g @SLOT2+0 [0,393216) overlaps h [98304,294912) but h is dead. OK)
  //  out GEMM/ep:         pf_out @SLOT1 [786432] (pf_f2 dead), reads g @SLOT2.
  float* pf_fg   = ws + SLOT1;
  float* forget  = ws + SLOT2;
  float* query   = ws + SLOT2 + 98304;
  float* keyv    = ws + SLOT2 + 196608;
  float* value   = ws + SLOT2 + 294912;
  float* attn    = ws + SLOT2;             // reuse (forget dead after scan)
  float* pf_proj = ws + SLOT1;
  float* h2      = ws + SLOT2 + 98304;     // [196608] (q/k/v dead after scan)
  float* pf1     = ws + SLOT0;             // [786432]
  float* pf2     = ws + SLOT1;             // [786432]
  float* g       = ws + SLOT2;             // [393216] (attn/h dead by ep_ffng)
  float* pf_o    = ws + SLOT1;             // [786432] (pf2 dead after ep_ffng)

  // 1) forget GEMM (fused mixed), S=4 -> pf_fg[4][256][384]
  gemm_forget_sk<4><<<dim3(4, Q_D / 64, 4), 512, 0, stream>>>(inp, is_first, init_inp,
                                                              mix_mu, mix_W, pf_fg);
  ep_forget<<<NTOK * Q_D / 256, 256, 0, stream>>>(pf_fg, drops, forget);

  // 2) parts GEMM, S=2 -> pf_parts[2][256][1536]
  gemm_sk<INP_D, DFF_D, 2><<<dim3(4, DFF_D / 64, 2), 512, 0, stream>>>(inp, layer_W, pf_parts);
  ep_qkv<<<NTOK * Q_D / 256, 256, 0, stream>>>(pf_parts, drops, query, keyv, value);

  // 3) scan -> patt[8][256][384]
  k_scan<<<dim3(E_D / 64, 8, B_DIM), 256, 0, stream>>>(forget, query, keyv, value,
                                                       is_first, init_state, patt);
  ep_rms<<<NTOK, 128, 0, stream>>>(patt, rms_w, attn);

  // 4) proj GEMM, S=4 -> pf_proj[4][256][768]
  gemm_sk<E_D, INP_D, 4><<<dim3(4, INP_D / 64, 4), 512, 0, stream>>>(attn, proj_W, pf_proj);
  ep_ln<<<NTOK, 256, 0, stream>>>(pf_proj, inp, ln_w, ln_b, h2);

  // 5) FFN dual GEMM, S=2 -> pf1/pf2 [2][256][1536]
  gemm_ffn_sk<2><<<dim3(4, DFF_D / 64, 2), 512, 0, stream>>>(h2, W1, W2, pf1, pf2);
  ep_ffng<<<NTOK * DFF_D / 256, 256, 0, stream>>>(pf1, pf2, g);

  // 6) out GEMM, S=4 -> pf_o[4][256][768]
  gemm_sk<DFF_D, INP_D, 4><<<dim3(4, INP_D / 64, 4), 512, 0, stream>>>(g, W3, pf_o);
  ep_out<<<NTOK * INP_D / 256, 256, 0, stream>>>(pf_o, out);
}